// Round 1
// baseline (218.420 us; speedup 1.0000x reference)
//
#include <hip/hip_runtime.h>
#include <stdint.h>

// channel-gather lists for the 16 branch convs
constexpr int IDX3[18] = {0,1,2, 1,2,3, 2,3,4, 3,4,5, 0,4,5, 0,1,5};
constexpr int IDX4[36] = {0,1,2,3, 1,2,3,4, 2,3,4,5, 0,3,4,5, 0,1,4,5,
                          0,1,2,5, 0,1,3,4, 1,2,4,5, 0,2,3,5};

// ws layout (uint32 units):
//   [0..90)      w3 Wp masks   (br*15 + ch*5 + r), 5-bit row masks
//   [90..270)    w4 Wp masks   (br*20 + ch*5 + r)
//   [270..300)   w6 Wp masks   (ch*5 + r)
//   [300..1860)  c5 Wp masks   (oc*13 + word), 400 bits per oc
//   [1860.. )    h5 bits: 4 u32 per image

__global__ void prepack_kernel(const float* __restrict__ w3, const float* __restrict__ w4,
                               const float* __restrict__ w6, const float* __restrict__ c5w,
                               unsigned* __restrict__ ws) {
    int t = blockIdx.x * blockDim.x + threadIdx.x;
    if (t < 300) {
        const float* src = (t < 90) ? (w3 + t * 5)
                          : (t < 270) ? (w4 + (t - 90) * 5)
                          : (w6 + (t - 270) * 5);
        unsigned m = 0;
        for (int p = 0; p < 5; ++p) if (src[p] > 0.f) m |= 1u << p;
        ws[t] = m;
    } else if (t < 1860) {
        int q = t - 300, oc = q / 13, w = q % 13;
        unsigned m = 0;
        for (int b = 0; b < 32; ++b) {
            int idx = w * 32 + b;
            if (idx < 400 && c5w[oc * 400 + idx] > 0.f) m |= 1u << b;
        }
        ws[300 + q] = m;
    }
}

__global__ __launch_bounds__(256) void lenet_a(
    const float* __restrict__ x, const float* __restrict__ c1w, const float* __restrict__ c1b,
    const float* __restrict__ b3, const float* __restrict__ b4, const float* __restrict__ b6,
    const float* __restrict__ c5b, const unsigned* __restrict__ ws,
    unsigned* __restrict__ h5out, int B) {
    __shared__ float xs[3 * 1024];
    __shared__ float wS[150];
    __shared__ float bS[6];
    __shared__ float b3S[6];
    __shared__ float b4S[9];
    __shared__ float b6S[1];
    __shared__ unsigned hrow[3][6][14];   // 14-bit pooled-sign rows of stage 1
    __shared__ unsigned sbits[3][100];    // per-pixel 16-bit branch sign masks
    __shared__ unsigned c5in[3][16];      // 400-bit c5 input (padded)
    __shared__ unsigned h5[3][4];         // 120-bit c5 output

    const int t = threadIdx.x;
    const int img0 = blockIdx.x * 3;
    const int nimg = min(3, B - img0);

    // ---- phase 0: stage inputs ----
    for (int i = t; i < nimg * 256; i += 256)
        ((float4*)xs)[i] = ((const float4*)(x + (size_t)img0 * 1024))[i];
    if (t < 150) wS[t] = c1w[t];
    if (t < 6) { bS[t] = c1b[t]; b3S[t] = b3[t]; }
    if (t < 9) b4S[t] = b4[t];
    if (t == 0) b6S[0] = b6[0];
    if (t < 48) ((unsigned*)c5in)[t] = 0;
    if (t < 12) ((unsigned*)h5)[t] = 0;
    __syncthreads();

    // ---- phase 1: c1 conv + relu + pool + sign, one thread per (img, ch, pooled row) ----
    if (t < nimg * 84) {
        int img = t / 84, rest = t % 84, c = rest / 14, py = rest % 14;
        float wr[25];
        #pragma unroll
        for (int i = 0; i < 25; ++i) wr[i] = wS[c * 25 + i];
        const float bias = bS[c];
        float a0[28], a1[28];
        #pragma unroll
        for (int j = 0; j < 28; ++j) { a0[j] = bias; a1[j] = bias; }
        const float* xp = xs + img * 1024 + 2 * py * 32;
        #pragma unroll
        for (int r = 0; r < 6; ++r) {
            float rv[32];
            #pragma unroll
            for (int q = 0; q < 8; ++q) {
                float4 v = ((const float4*)(xp + r * 32))[q];
                rv[4 * q] = v.x; rv[4 * q + 1] = v.y; rv[4 * q + 2] = v.z; rv[4 * q + 3] = v.w;
            }
            if (r <= 4) {
                #pragma unroll
                for (int kw = 0; kw < 5; ++kw) {
                    float wv = wr[r * 5 + kw];
                    #pragma unroll
                    for (int cx = 0; cx < 28; ++cx) a0[cx] = fmaf(rv[cx + kw], wv, a0[cx]);
                }
            }
            if (r >= 1) {
                #pragma unroll
                for (int kw = 0; kw < 5; ++kw) {
                    float wv = wr[(r - 1) * 5 + kw];
                    #pragma unroll
                    for (int cx = 0; cx < 28; ++cx) a1[cx] = fmaf(rv[cx + kw], wv, a1[cx]);
                }
            }
        }
        unsigned m = 0;
        #pragma unroll
        for (int px = 0; px < 14; ++px) {
            float mx = fmaxf(fmaxf(a0[2 * px], a0[2 * px + 1]), fmaxf(a1[2 * px], a1[2 * px + 1]));
            if (mx > 0.f) m |= 1u << px;  // avgpool(relu)>0 <=> any conv>0
        }
        hrow[img][c][py] = m;
    }
    __syncthreads();

    // ---- phase 2: 16 binary branch convs at each 10x10 pixel (shared-shift popcounts) ----
    const int ntask2 = nimg * 100;
    for (int q = t; q < ntask2; q += 256) {
        int img = q / 100, p = q % 100, oy = p / 10, ox = p % 10;
        unsigned s[6][5];
        int wpop[6];
        #pragma unroll
        for (int c = 0; c < 6; ++c) {
            wpop[c] = 0;
            #pragma unroll
            for (int r = 0; r < 5; ++r) {
                unsigned v = (hrow[img][c][oy + r] >> ox) & 31u;
                s[c][r] = v;
                wpop[c] += __popc(v);
            }
        }
        unsigned m16 = 0;
        #pragma unroll
        for (int br = 0; br < 6; ++br) {
            int sum = 0, tot = 0;
            #pragma unroll
            for (int j = 0; j < 3; ++j) {
                int c = IDX3[br * 3 + j];
                tot += wpop[c];
                #pragma unroll
                for (int r = 0; r < 5; ++r) sum += __popc(s[c][r] & ws[br * 15 + j * 5 + r]);
            }
            if ((float)(2 * sum - tot) + b3S[br] > 0.f) m16 |= 1u << br;
        }
        #pragma unroll
        for (int br = 0; br < 9; ++br) {
            int sum = 0, tot = 0;
            #pragma unroll
            for (int j = 0; j < 4; ++j) {
                int c = IDX4[br * 4 + j];
                tot += wpop[c];
                #pragma unroll
                for (int r = 0; r < 5; ++r) sum += __popc(s[c][r] & ws[90 + br * 20 + j * 5 + r]);
            }
            if ((float)(2 * sum - tot) + b4S[br] > 0.f) m16 |= 1u << (6 + br);
        }
        {
            int sum = 0, tot = 0;
            #pragma unroll
            for (int c = 0; c < 6; ++c) {
                tot += wpop[c];
                #pragma unroll
                for (int r = 0; r < 5; ++r) sum += __popc(s[c][r] & ws[270 + c * 5 + r]);
            }
            if ((float)(2 * sum - tot) + b6S[0] > 0.f) m16 |= 1u << 15;
        }
        sbits[img][p] = m16;
    }
    __syncthreads();

    // ---- phase 2b: relu+avgpool+sign -> 400-bit c5 input ----
    for (int q = t; q < nimg * 400; q += 256) {
        int img = q / 400, rest = q % 400, oc = rest / 25, qi = rest % 25, qy = qi / 5, qx = qi % 5;
        int base = (2 * qy) * 10 + 2 * qx;
        unsigned any = sbits[img][base] | sbits[img][base + 1] |
                       sbits[img][base + 10] | sbits[img][base + 11];
        if ((any >> oc) & 1u)
            atomicOr(&c5in[img][rest >> 5], 1u << (rest & 31));
    }
    __syncthreads();

    // ---- phase 3: c5 binary conv -> 120 sign bits ----
    for (int q = t; q < nimg * 120; q += 256) {
        int img = q / 120, oc = q % 120;
        const unsigned* cm = ws + 300 + oc * 13;
        int sum = 0, tot = 0;
        #pragma unroll
        for (int w = 0; w < 13; ++w) {
            unsigned inw = c5in[img][w];
            tot += __popc(inw);
            sum += __popc(inw & cm[w]);
        }
        if ((float)(2 * sum - tot) + c5b[oc] > 0.f)
            atomicOr(&h5[img][oc >> 5], 1u << (oc & 31));
    }
    __syncthreads();

    if (t < nimg * 4) h5out[(size_t)img0 * 4 + t] = ((unsigned*)h5)[t];
}

__global__ __launch_bounds__(256) void lenet_b(
    const unsigned* __restrict__ h5, const float* __restrict__ f6w, const float* __restrict__ f6b,
    const float* __restrict__ rbfw, const float* __restrict__ rbfb, float* __restrict__ out) {
    __shared__ float wS[84 * 120];
    __shared__ float f6o[32][84];
    __shared__ float rwS[840];
    __shared__ float fbS[84];
    __shared__ float rbS[10];
    __shared__ unsigned hS[32][4];

    const int t = threadIdx.x;
    const int img0 = blockIdx.x * 32;
    for (int i = t; i < 2520; i += 256) ((float4*)wS)[i] = ((const float4*)f6w)[i];
    for (int i = t; i < 210; i += 256) ((float4*)rwS)[i] = ((const float4*)rbfw)[i];
    if (t < 84) fbS[t] = f6b[t];
    if (t < 10) rbS[t] = rbfb[t];
    if (t < 128) ((unsigned*)hS)[t] = h5[(size_t)img0 * 4 + t];
    __syncthreads();

    const int g = t >> 5;   // image group: 4 images
    const int jc = t & 31;  // j-chunk: 3 rows of f6
    if (jc < 28) {
        const int j0 = 3 * jc;
        float acc[3][4];
        #pragma unroll
        for (int jj = 0; jj < 3; ++jj) {
            float b = fbS[j0 + jj];
            #pragma unroll
            for (int i = 0; i < 4; ++i) acc[jj][i] = b;
        }
        unsigned bb[4][4];
        #pragma unroll
        for (int i = 0; i < 4; ++i) {
            #pragma unroll
            for (int w = 0; w < 4; ++w) bb[i][w] = hS[g * 4 + i][w];
        }
        #pragma unroll
        for (int kw = 0; kw < 4; ++kw) {
            const unsigned m0 = bb[0][kw], m1 = bb[1][kw], m2 = bb[2][kw], m3 = bb[3][kw];
            const int kmax = (kw == 3) ? 24 : 32;
            #pragma unroll 4
            for (int kb = 0; kb < kmax; ++kb) {
                int k = kw * 32 + kb;
                float f0 = wS[(j0 + 0) * 120 + k];
                float f1 = wS[(j0 + 1) * 120 + k];
                float f2 = wS[(j0 + 2) * 120 + k];
                bool o0 = (m0 >> kb) & 1u, o1 = (m1 >> kb) & 1u;
                bool o2 = (m2 >> kb) & 1u, o3 = (m3 >> kb) & 1u;
                acc[0][0] += o0 ? f0 : -f0; acc[1][0] += o0 ? f1 : -f1; acc[2][0] += o0 ? f2 : -f2;
                acc[0][1] += o1 ? f0 : -f0; acc[1][1] += o1 ? f1 : -f1; acc[2][1] += o1 ? f2 : -f2;
                acc[0][2] += o2 ? f0 : -f0; acc[1][2] += o2 ? f1 : -f1; acc[2][2] += o2 ? f2 : -f2;
                acc[0][3] += o3 ? f0 : -f0; acc[1][3] += o3 ? f1 : -f1; acc[2][3] += o3 ? f2 : -f2;
            }
        }
        #pragma unroll
        for (int jj = 0; jj < 3; ++jj) {
            #pragma unroll
            for (int i = 0; i < 4; ++i)
                f6o[g * 4 + i][j0 + jj] = tanhf(1.7519f * acc[jj][i]);
        }
    }
    __syncthreads();

    for (int q = t; q < 320; q += 256) {
        int im = q / 10, oc = q % 10;
        float sum = rbS[oc];
        #pragma unroll 4
        for (int j = 0; j < 84; ++j) sum = fmaf(f6o[im][j], rwS[oc * 84 + j], sum);
        out[(size_t)(img0 + im) * 10 + oc] = fmaxf(sum, 0.f);
    }
}

extern "C" void kernel_launch(void* const* d_in, const int* in_sizes, int n_in,
                              void* d_out, int out_size, void* d_ws, size_t ws_size,
                              hipStream_t stream) {
    const float* x    = (const float*)d_in[0];
    const float* c1w  = (const float*)d_in[1];
    const float* c1b  = (const float*)d_in[2];
    const float* w3   = (const float*)d_in[3];
    const float* b3   = (const float*)d_in[4];
    const float* w4   = (const float*)d_in[5];
    const float* b4   = (const float*)d_in[6];
    const float* w6   = (const float*)d_in[7];
    const float* b6   = (const float*)d_in[8];
    const float* c5w  = (const float*)d_in[9];
    const float* c5b  = (const float*)d_in[10];
    const float* f6w  = (const float*)d_in[11];
    const float* f6b  = (const float*)d_in[12];
    const float* rbfw = (const float*)d_in[13];
    const float* rbfb = (const float*)d_in[14];
    const int B = in_sizes[0] / 1024;

    unsigned* ws = (unsigned*)d_ws;
    unsigned* h5 = ws + 1860;

    prepack_kernel<<<dim3(8), dim3(256), 0, stream>>>(w3, w4, w6, c5w, ws);
    lenet_a<<<dim3((B + 2) / 3), dim3(256), 0, stream>>>(x, c1w, c1b, b3, b4, b6, c5b, ws, h5, B);
    lenet_b<<<dim3(B / 32), dim3(256), 0, stream>>>(h5, f6w, f6b, rbfw, rbfb, (float*)d_out);
}

// Round 2
// 153.528 us; speedup vs baseline: 1.4227x; 1.4227x over previous
//
#include <hip/hip_runtime.h>
#include <stdint.h>

// channel-gather lists for the 16 branch convs
constexpr int IDX3[18] = {0,1,2, 1,2,3, 2,3,4, 3,4,5, 0,4,5, 0,1,5};
constexpr int IDX4[36] = {0,1,2,3, 1,2,3,4, 2,3,4,5, 0,3,4,5, 0,1,4,5,
                          0,1,2,5, 0,1,3,4, 1,2,4,5, 0,2,3,5};

// ws layout (uint32 units):
//   [0..18)     w3 25-bit masks (br*3+j)
//   [18..54)    w4 25-bit masks (br*4+j)
//   [54..60)    w6 25-bit masks (c)
//   [60..1620)  c5 masks, 13 u32 per oc; bit g=w*32+b -> qi=g>>4, ic=g&15

__global__ void prepack_kernel(const float* __restrict__ w3, const float* __restrict__ w4,
                               const float* __restrict__ w6, const float* __restrict__ c5w,
                               unsigned* __restrict__ ws) {
    int t = blockIdx.x * blockDim.x + threadIdx.x;
    if (t < 60) {
        const float* src = (t < 18) ? (w3 + t * 25)
                          : (t < 54) ? (w4 + (t - 18) * 25)
                          : (w6 + (t - 54) * 25);
        unsigned m = 0;
        for (int p = 0; p < 25; ++p) if (src[p] > 0.f) m |= 1u << p;
        ws[t] = m;
    } else if (t < 1620) {
        int q = t - 60, oc = q / 13, w = q % 13;
        unsigned m = 0;
        for (int b = 0; b < 32; ++b) {
            int g = w * 32 + b;           // bit position = qi*16 + ic
            int qi = g >> 4, ic = g & 15;
            if (qi < 25 && c5w[oc * 400 + ic * 25 + qi] > 0.f) m |= 1u << b;
        }
        ws[60 + q] = m;
    }
}

// padded image tile: row stride 36 floats (bank +4/row), img stride 1156 (bank +4/img)
#define ROWS 36
#define IMGS 1156

__global__ __launch_bounds__(256) void lenet_fused(
    const float* __restrict__ x, const float* __restrict__ c1w, const float* __restrict__ c1b,
    const float* __restrict__ b3, const float* __restrict__ b4, const float* __restrict__ b6,
    const float* __restrict__ c5b, const unsigned* __restrict__ ws,
    const float* __restrict__ f6w, const float* __restrict__ f6b,
    const float* __restrict__ rbfw, const float* __restrict__ rbfb,
    float* __restrict__ out, int B) {
    __shared__ float xs[3 * IMGS];
    __shared__ float wS[150];
    __shared__ float bS[6], b3S[6], b4S[9], b6S[1];
    __shared__ unsigned hrow[3][6][14];   // 14-bit pooled-sign rows of stage 1
    __shared__ unsigned sbits[3][100];    // per-pixel 16-bit branch sign masks
    __shared__ unsigned c5in[3][13];      // 400-bit c5 input, bit = qi*16+ic
    __shared__ unsigned h5[3][4];         // 120-bit c5 output
    __shared__ float f6o[3][84];

    const int t = threadIdx.x;
    const int img0 = blockIdx.x * 3;
    const int nimg = min(3, B - img0);

    // ---- phase 0: stage x into padded LDS tile ----
    {
        const float4* src = (const float4*)(x + (size_t)img0 * 1024);
        for (int i = t; i < nimg * 256; i += 256) {
            int img = i >> 8, r = (i >> 3) & 31, q = i & 7;
            ((float4*)xs)[img * 289 + r * 9 + q] = src[i];
        }
    }
    if (t < 150) wS[t] = c1w[t];
    if (t < 6) { bS[t] = c1b[t]; b3S[t] = b3[t]; }
    if (t < 9) b4S[t] = b4[t];
    if (t == 0) b6S[0] = b6[0];
    if (t < 12) ((unsigned*)h5)[t] = 0;
    __syncthreads();

    // ---- phase 1: c1 conv + relu + pool + sign ----
    // mapping t = py*(6*nimg) + img*6 + c: a wave holds <=4 py groups ->
    // xs read bank offsets {4*img + 8*py} are <=2-way aliased (free).
    if (t < nimg * 84) {
        const int denom = nimg * 6;
        int py = t / denom, rem = t % denom, img = rem / 6, c = rem % 6;
        float wr[25];
        #pragma unroll
        for (int i = 0; i < 25; ++i) wr[i] = wS[c * 25 + i];
        const float bias = bS[c];
        float a0[28], a1[28];
        #pragma unroll
        for (int j = 0; j < 28; ++j) { a0[j] = bias; a1[j] = bias; }
        const float* xp = xs + img * IMGS + (2 * py) * ROWS;
        #pragma unroll
        for (int r = 0; r < 6; ++r) {
            float rv[32];
            #pragma unroll
            for (int q = 0; q < 8; ++q) {
                float4 v = ((const float4*)(xp + r * ROWS))[q];
                rv[4 * q] = v.x; rv[4 * q + 1] = v.y; rv[4 * q + 2] = v.z; rv[4 * q + 3] = v.w;
            }
            if (r <= 4) {
                #pragma unroll
                for (int kw = 0; kw < 5; ++kw) {
                    float wv = wr[r * 5 + kw];
                    #pragma unroll
                    for (int cx = 0; cx < 28; ++cx) a0[cx] = fmaf(rv[cx + kw], wv, a0[cx]);
                }
            }
            if (r >= 1) {
                #pragma unroll
                for (int kw = 0; kw < 5; ++kw) {
                    float wv = wr[(r - 1) * 5 + kw];
                    #pragma unroll
                    for (int cx = 0; cx < 28; ++cx) a1[cx] = fmaf(rv[cx + kw], wv, a1[cx]);
                }
            }
        }
        unsigned m = 0;
        #pragma unroll
        for (int px = 0; px < 14; ++px) {
            float mx = fmaxf(fmaxf(a0[2 * px], a0[2 * px + 1]), fmaxf(a1[2 * px], a1[2 * px + 1]));
            if (mx > 0.f) m |= 1u << px;  // avgpool(relu)>0 <=> any conv>0
        }
        hrow[img][c][py] = m;
    }
    __syncthreads();

    // ---- phase 2: 16 binary branch convs per 10x10 pixel, 25-bit packed popcounts ----
    for (int q = t; q < nimg * 100; q += 256) {
        int img = q / 100, p = q % 100, oy = p / 10, ox = p % 10;
        unsigned win[6];
        int wpop[6];
        #pragma unroll
        for (int c = 0; c < 6; ++c) {
            unsigned w = 0;
            #pragma unroll
            for (int r = 0; r < 5; ++r)
                w |= ((hrow[img][c][oy + r] >> ox) & 31u) << (5 * r);
            win[c] = w;
            wpop[c] = __popc(w);
        }
        unsigned m16 = 0;
        #pragma unroll
        for (int br = 0; br < 6; ++br) {
            int sum = 0, tot = 0;
            #pragma unroll
            for (int j = 0; j < 3; ++j) {
                int c = IDX3[br * 3 + j];
                tot += wpop[c];
                sum += __popc(win[c] & ws[br * 3 + j]);
            }
            if ((float)(2 * sum - tot) + b3S[br] > 0.f) m16 |= 1u << br;
        }
        #pragma unroll
        for (int br = 0; br < 9; ++br) {
            int sum = 0, tot = 0;
            #pragma unroll
            for (int j = 0; j < 4; ++j) {
                int c = IDX4[br * 4 + j];
                tot += wpop[c];
                sum += __popc(win[c] & ws[18 + br * 4 + j]);
            }
            if ((float)(2 * sum - tot) + b4S[br] > 0.f) m16 |= 1u << (6 + br);
        }
        {
            int sum = 0, tot = 0;
            #pragma unroll
            for (int c = 0; c < 6; ++c) {
                tot += wpop[c];
                sum += __popc(win[c] & ws[54 + c]);
            }
            if ((float)(2 * sum - tot) + b6S[0] > 0.f) m16 |= 1u << 15;
        }
        sbits[img][p] = m16;
    }
    __syncthreads();

    // ---- phase 2b: relu+pool+sign -> 400-bit c5 input, word-at-a-time (no atomics) ----
    for (int q = t; q < nimg * 13; q += 256) {
        int img = q / 13, j = q % 13;
        int qi0 = 2 * j;
        int qy = qi0 / 5, qx = qi0 % 5, base = 2 * qy * 10 + 2 * qx;
        unsigned a0 = sbits[img][base] | sbits[img][base + 1] |
                      sbits[img][base + 10] | sbits[img][base + 11];
        unsigned word = a0 & 0xFFFFu;
        if (j < 12) {
            int qi1 = qi0 + 1;
            qy = qi1 / 5; qx = qi1 % 5; base = 2 * qy * 10 + 2 * qx;
            unsigned a1 = sbits[img][base] | sbits[img][base + 1] |
                          sbits[img][base + 10] | sbits[img][base + 11];
            word |= (a1 & 0xFFFFu) << 16;
        }
        c5in[img][j] = word;
    }
    __syncthreads();

    // ---- phase 3: c5 binary conv -> 120 sign bits ----
    for (int q = t; q < nimg * 120; q += 256) {
        int img = q / 120, oc = q % 120;
        const unsigned* cm = ws + 60 + oc * 13;
        int sum = 0, tot = 0;
        #pragma unroll
        for (int w = 0; w < 13; ++w) {
            unsigned inw = c5in[img][w];
            tot += __popc(inw);
            sum += __popc(inw & cm[w]);
        }
        if ((float)(2 * sum - tot) + c5b[oc] > 0.f)
            atomicOr(&h5[img][oc >> 5], 1u << (oc & 31));
    }
    __syncthreads();

    // ---- phase 4: f6 (+-1 dot, 120 wide) + tanh ----
    if (t < nimg * 84) {
        int img = t / 84, j = t % 84;
        unsigned hw[4];
        #pragma unroll
        for (int w = 0; w < 4; ++w) hw[w] = h5[img][w];
        float acc = f6b[j];
        const float4* wrow = (const float4*)f6w + j * 30;
        #pragma unroll
        for (int kk = 0; kk < 30; ++kk) {
            float4 wv = wrow[kk];
            int k = 4 * kk;
            acc += ((hw[(k + 0) >> 5] >> ((k + 0) & 31)) & 1u) ? wv.x : -wv.x;
            acc += ((hw[(k + 1) >> 5] >> ((k + 1) & 31)) & 1u) ? wv.y : -wv.y;
            acc += ((hw[(k + 2) >> 5] >> ((k + 2) & 31)) & 1u) ? wv.z : -wv.z;
            acc += ((hw[(k + 3) >> 5] >> ((k + 3) & 31)) & 1u) ? wv.w : -wv.w;
        }
        f6o[img][j] = tanhf(1.7519f * acc);
    }
    __syncthreads();

    // ---- phase 5: rbf + relu -> out ----
    if (t < nimg * 10) {
        int img = t / 10, oc = t % 10;
        float sum = rbfb[oc];
        #pragma unroll 4
        for (int j = 0; j < 84; ++j) sum = fmaf(f6o[img][j], rbfw[oc * 84 + j], sum);
        out[(size_t)(img0 + img) * 10 + oc] = fmaxf(sum, 0.f);
    }
}

extern "C" void kernel_launch(void* const* d_in, const int* in_sizes, int n_in,
                              void* d_out, int out_size, void* d_ws, size_t ws_size,
                              hipStream_t stream) {
    const float* x    = (const float*)d_in[0];
    const float* c1w  = (const float*)d_in[1];
    const float* c1b  = (const float*)d_in[2];
    const float* w3   = (const float*)d_in[3];
    const float* b3   = (const float*)d_in[4];
    const float* w4   = (const float*)d_in[5];
    const float* b4   = (const float*)d_in[6];
    const float* w6   = (const float*)d_in[7];
    const float* b6   = (const float*)d_in[8];
    const float* c5w  = (const float*)d_in[9];
    const float* c5b  = (const float*)d_in[10];
    const float* f6w  = (const float*)d_in[11];
    const float* f6b  = (const float*)d_in[12];
    const float* rbfw = (const float*)d_in[13];
    const float* rbfb = (const float*)d_in[14];
    const int B = in_sizes[0] / 1024;

    unsigned* ws = (unsigned*)d_ws;

    prepack_kernel<<<dim3(7), dim3(256), 0, stream>>>(w3, w4, w6, c5w, ws);
    lenet_fused<<<dim3((B + 2) / 3), dim3(256), 0, stream>>>(
        x, c1w, c1b, b3, b4, b6, c5b, ws, f6w, f6b, rbfw, rbfb, (float*)d_out, B);
}